// Round 6
// baseline (113.348 us; speedup 1.0000x reference)
//
#include <hip/hip_runtime.h>

#define HH 16
#define TT 4096
#define DD 64

typedef __attribute__((ext_vector_type(4))) _Float16 half4;
typedef __attribute__((ext_vector_type(4))) float float4v;

// One block = 4 waves x 32 q rows = 128 q rows of one head; grid 512 (2/CU).
// Double-buffered 64-key K/V tiles in LDS, single barrier per tile.
// LDS layout (both K[key][d] and Vt[d][key], 64 rows x 128 B):
//   phys(row, o8) = row*128 + 16*((o8>>1)^(row&7)) + 8*((o8&1)^((row>>3)&1))
// -> every 16-lane quarter of a b64 fragment read hits all 32 banks once.
// V staged transposed via fully-coalesced dword gathers (lane = d column).
__global__ __launch_bounds__(256, 2) void pa_fwd(
    const float* __restrict__ qg, const float* __restrict__ kg,
    const float* __restrict__ vg, const int* __restrict__ cu,
    float* __restrict__ outg)
{
    __shared__ __align__(16) _Float16 Kl[2][64 * 64];
    __shared__ __align__(16) _Float16 Vl[2][64 * 64];

    const int tid  = threadIdx.x;
    const int lane = tid & 63;
    const int wave = tid >> 6;      // 0..3
    const int lr   = lane & 15;
    const int lg   = lane >> 4;

    // XCD swizzle: grid 512 = 8 XCD x 64 contiguous work items (2 heads/XCD)
    const int bswz = ((int)blockIdx.x & 7) * 64 + ((int)blockIdx.x >> 3);
    const int h    = bswz >> 5;
    const int qblk = (bswz & 31) << 7;     // 128 q rows per block
    const int qb   = qblk + wave * 32;     // 32 q rows per wave
    const int q0   = qb + lr;
    const int q1   = qb + 16 + lr;

    // segment bounds (searchsorted semantics)
    int s = 0;
    while (cu[s + 1] <= q0) ++s;
    const int lo0 = cu[s], hi0 = cu[s + 1];
    while (cu[s + 1] <= q1) ++s;
    const int lo1 = cu[s], hi1 = cu[s + 1];

    int sb = 0;
    while (cu[sb + 1] <= qblk) ++sb;
    const int blo = cu[sb];
    while (cu[sb + 1] <= qblk + 127) ++sb;
    const int bhi = cu[sb + 1];

    const int wlo = __shfl(lo0, 0);    // wave min key
    const int whi = __shfl(hi1, 15);   // wave max key
    const int mlo = __shfl(lo1, 15);   // max lo over wave rows
    const int mhi = __shfl(hi0, 0);    // min hi over wave rows

    // Q fragments (B operand), pre-scaled by 1/sqrt(64)
    const float* qrow0 = qg + ((size_t)h * TT + q0) * DD;
    const float* qrow1 = qg + ((size_t)h * TT + q1) * DD;
    half4 qf0[4], qf1[4];
#pragma unroll
    for (int ds = 0; ds < 4; ++ds) {
        float4v t0 = *(const float4v*)(qrow0 + ds * 16 + lg * 4);
        float4v t1 = *(const float4v*)(qrow1 + ds * 16 + lg * 4);
#pragma unroll
        for (int j = 0; j < 4; ++j) {
            qf0[ds][j] = (_Float16)(t0[j] * 0.125f);
            qf1[ds][j] = (_Float16)(t1[j] * 0.125f);
        }
    }

    const float* kh_ = kg + (size_t)h * TT * DD;
    const float* vh_ = vg + (size_t)h * TT * DD;

    // staging assignments
    const int srow = tid >> 2;          // K key row 0..63
    const int sch  = (tid & 3) << 4;    // K float chunk base (16 floats)
    const int vd   = tid & 63;          // Vt row (d column of V)

    // swizzled write offsets (bytes, loop-invariant)
    unsigned kwr[4], vwr[4];
#pragma unroll
    for (int i = 0; i < 4; ++i) {
        const int ko8 = (tid & 3) * 4 + i;
        kwr[i] = (unsigned)(srow * 128 + 16 * ((ko8 >> 1) ^ (srow & 7)) +
                            8 * ((ko8 & 1) ^ ((srow >> 3) & 1)));
        const int vo8 = wave * 4 + i;
        vwr[i] = (unsigned)(vd * 128 + 16 * ((vo8 >> 1) ^ (vd & 7)) +
                            8 * ((vo8 & 1) ^ ((vd >> 3) & 1)));
    }
    // swizzled fragment-read bases (bytes): rbase[x] + y*2048
    unsigned rbase[4];
#pragma unroll
    for (int i = 0; i < 4; ++i)
        rbase[i] = (unsigned)(lr * 128 + 16 * (((2 * i + (lg >> 1))) ^ (lr & 7)) +
                              8 * ((lg & 1) ^ ((lr >> 3) & 1)));

    // prefetch registers
    float4v kq[4];
    float vv[16];

    const int t0k = blo & ~63;
#define ISSUE(KT)                                                              \
    {                                                                          \
        int krow = (KT) + srow; if (krow > TT - 1) krow = TT - 1;              \
        const float4v* kp = (const float4v*)(kh_ + (size_t)krow * DD + sch);   \
        kq[0] = kp[0]; kq[1] = kp[1]; kq[2] = kp[2]; kq[3] = kp[3];            \
        _Pragma("unroll")                                                      \
        for (int c = 0; c < 16; ++c) {                                         \
            int vrow = (KT) + wave * 16 + c; if (vrow > TT - 1) vrow = TT - 1; \
            vv[c] = vh_[(size_t)vrow * DD + vd];                               \
        }                                                                      \
    }

    ISSUE(t0k);

    float4v acc0[4], acc1[4];
#pragma unroll
    for (int dt = 0; dt < 4; ++dt) { acc0[dt] = (float4v){0,0,0,0}; acc1[dt] = (float4v){0,0,0,0}; }
    float m0 = -1e30f, l0 = 0.f, m1 = -1e30f, l1 = 0.f;

    int cur = 0;
    for (int kt = t0k; kt < bhi; kt += 64) {
        // ---- pack + write LDS buf[cur] ----
        {
            char* Kb = (char*)Kl[cur];
            char* Vb = (char*)Vl[cur];
#pragma unroll
            for (int i = 0; i < 4; ++i) {
                half4 hk;
#pragma unroll
                for (int m = 0; m < 4; ++m) hk[m] = (_Float16)kq[i][m];
                *(half4*)(Kb + kwr[i]) = hk;
            }
#pragma unroll
            for (int i = 0; i < 4; ++i) {
                half4 hv;
#pragma unroll
                for (int m = 0; m < 4; ++m) hv[m] = (_Float16)vv[4 * i + m];
                *(half4*)(Vb + vwr[i]) = hv;
            }
        }
        __syncthreads();   // the only barrier per tile

        if (kt + 64 < bhi) ISSUE(kt + 64);   // wave-uniform

        if (!(kt + 64 <= wlo || kt >= whi)) {
            const char* Kb = (const char*)Kl[cur];
            const char* Vb = (const char*)Vl[cur];

            // ---- QK^T: St[key][q], 4 x 16-key quarters, both q frags ----
            float st0[4][4], st1[4][4];
            const bool fullv = (kt >= mlo) && (kt + 64 <= mhi);  // wave-uniform
#pragma unroll
            for (int t = 0; t < 4; ++t) {
                float4v sa0 = (float4v){0,0,0,0}, sa1 = (float4v){0,0,0,0};
#pragma unroll
                for (int ds = 0; ds < 4; ++ds) {
                    half4 kf = *(const half4*)(Kb + rbase[ds] + t * 2048);
                    sa0 = __builtin_amdgcn_mfma_f32_16x16x16f16(kf, qf0[ds], sa0, 0, 0, 0);
                    sa1 = __builtin_amdgcn_mfma_f32_16x16x16f16(kf, qf1[ds], sa1, 0, 0, 0);
                }
                if (fullv) {
#pragma unroll
                    for (int j = 0; j < 4; ++j) { st0[t][j] = sa0[j]; st1[t][j] = sa1[j]; }
                } else {
#pragma unroll
                    for (int j = 0; j < 4; ++j) {
                        const int key = kt + t * 16 + lg * 4 + j;
                        st0[t][j] = (key >= lo0 && key < hi0) ? sa0[j] : -1e30f;
                        st1[t][j] = (key >= lo1 && key < hi1) ? sa1[j] : -1e30f;
                    }
                }
            }

            // ---- online softmax (per q row = lr; reduce over lg) ----
            float tx0 = -1e30f, tx1 = -1e30f;
#pragma unroll
            for (int t = 0; t < 4; ++t)
#pragma unroll
                for (int j = 0; j < 4; ++j) { tx0 = fmaxf(tx0, st0[t][j]); tx1 = fmaxf(tx1, st1[t][j]); }
            tx0 = fmaxf(tx0, __shfl_xor(tx0, 16)); tx0 = fmaxf(tx0, __shfl_xor(tx0, 32));
            tx1 = fmaxf(tx1, __shfl_xor(tx1, 16)); tx1 = fmaxf(tx1, __shfl_xor(tx1, 32));
            const float mn0 = fmaxf(m0, tx0), mn1 = fmaxf(m1, tx1);
            const float a0 = __expf(m0 - mn0), a1 = __expf(m1 - mn1);
            // all-masked tile self-heals at first valid tile (a=0 wipes acc,l)

            half4 pb0[4], pb1[4];
            float ps0 = 0.f, ps1 = 0.f;
#pragma unroll
            for (int t = 0; t < 4; ++t)
#pragma unroll
                for (int j = 0; j < 4; ++j) {
                    const float e0 = __expf(st0[t][j] - mn0);
                    const float e1 = __expf(st1[t][j] - mn1);
                    ps0 += e0; ps1 += e1;
                    pb0[t][j] = (_Float16)e0; pb1[t][j] = (_Float16)e1;
                }
            ps0 += __shfl_xor(ps0, 16); ps0 += __shfl_xor(ps0, 32);
            ps1 += __shfl_xor(ps1, 16); ps1 += __shfl_xor(ps1, 32);
            l0 = l0 * a0 + ps0; l1 = l1 * a1 + ps1;
            m0 = mn0; m1 = mn1;

#pragma unroll
            for (int dt = 0; dt < 4; ++dt)
#pragma unroll
                for (int j = 0; j < 4; ++j) { acc0[dt][j] *= a0; acc1[dt][j] *= a1; }

            // ---- PV: Ot += V^T * P^T ----
#pragma unroll
            for (int t = 0; t < 4; ++t)
#pragma unroll
                for (int dt = 0; dt < 4; ++dt) {
                    half4 vf = *(const half4*)(Vb + rbase[t] + dt * 2048);
                    acc0[dt] = __builtin_amdgcn_mfma_f32_16x16x16f16(vf, pb0[t], acc0[dt], 0, 0, 0);
                    acc1[dt] = __builtin_amdgcn_mfma_f32_16x16x16f16(vf, pb1[t], acc1[dt], 0, 0, 0);
                }
        }
        cur ^= 1;
    }

    const float inv0 = 1.0f / l0;
    const float inv1 = 1.0f / l1;
    float* orow0 = outg + ((size_t)h * TT + q0) * DD;
    float* orow1 = outg + ((size_t)h * TT + q1) * DD;
#pragma unroll
    for (int dt = 0; dt < 4; ++dt) {
        float4v o0, o1;
#pragma unroll
        for (int j = 0; j < 4; ++j) { o0[j] = acc0[dt][j] * inv0; o1[j] = acc1[dt][j] * inv1; }
        *(float4v*)(orow0 + dt * 16 + lg * 4) = o0;
        *(float4v*)(orow1 + dt * 16 + lg * 4) = o1;
    }
#undef ISSUE
}

extern "C" void kernel_launch(void* const* d_in, const int* in_sizes, int n_in,
                              void* d_out, int out_size, void* d_ws, size_t ws_size,
                              hipStream_t stream) {
    const float* q  = (const float*)d_in[0];
    const float* k  = (const float*)d_in[1];
    const float* v  = (const float*)d_in[2];
    const int*   cu = (const int*)d_in[3];
    float* out = (float*)d_out;

    dim3 grid(HH * (TT / 128));   // 512
    dim3 block(256);
    hipLaunchKernelGGL(pa_fwd, grid, block, 0, stream, q, k, v, cu, out);
}

// Round 7
// 91.101 us; speedup vs baseline: 1.2442x; 1.2442x over previous
//
#include <hip/hip_runtime.h>

#define HH 16
#define TT 4096
#define DD 64

typedef __attribute__((ext_vector_type(4))) _Float16 half4;
typedef __attribute__((ext_vector_type(4))) float float4v;

// One block = 4 waves x 16 q rows = 64 q rows of one head; grid 1024
// -> 4 blocks/CU, 16 waves/CU in 4 independent barrier groups.
// Double-buffered 64-key K/V tiles in LDS, single barrier per tile.
// LDS layout (K[key][d] and Vt[d][key], 64 rows x 128 B):
//   phys(row, o8) = row*128 + 16*((o8>>1)^(row&7)) + 8*((o8&1)^((row>>3)&1))
// -> quarter-wave of any b64 fragment read hits all 32 banks once (R6-proven:
//    conflicts ~2.7% of cycles). V staged transposed via coalesced dword
//    gathers (lane = d column). Defer-max + setprio added.
__global__ __launch_bounds__(256, 4) void pa_fwd(
    const float* __restrict__ qg, const float* __restrict__ kg,
    const float* __restrict__ vg, const int* __restrict__ cu,
    float* __restrict__ outg)
{
    __shared__ __align__(16) _Float16 Kl[2][64 * 64];
    __shared__ __align__(16) _Float16 Vl[2][64 * 64];

    const int tid  = threadIdx.x;
    const int lane = tid & 63;
    const int wave = tid >> 6;      // 0..3
    const int lr   = lane & 15;
    const int lg   = lane >> 4;

    // XCD swizzle: grid 1024 = 8 XCD x 128 contiguous work items
    const int bswz = ((int)blockIdx.x & 7) * 128 + ((int)blockIdx.x >> 3);
    const int h    = bswz >> 6;            // 0..15
    const int qblk = (bswz & 63) << 6;     // 64 q rows per block
    const int q    = qblk + wave * 16 + lr;

    // per-row segment bounds (searchsorted semantics)
    int s = 0;
    while (cu[s + 1] <= q) ++s;
    const int lo = cu[s], hi = cu[s + 1];

    // block-level staging range
    int sb = 0;
    while (cu[sb + 1] <= qblk) ++sb;
    const int blo = cu[sb];
    while (cu[sb + 1] <= qblk + 63) ++sb;
    const int bhi = cu[sb + 1];

    const int wlo = __shfl(lo, 0);    // wave min key
    const int whi = __shfl(hi, 15);   // wave max key
    const int mlo = __shfl(lo, 15);   // max lo over wave rows
    const int mhi = __shfl(hi, 0);    // min hi over wave rows

    // Q fragment (B operand), pre-scaled by 1/sqrt(64)
    const float* qrow = qg + ((size_t)h * TT + q) * DD;
    half4 qf[4];
#pragma unroll
    for (int ds = 0; ds < 4; ++ds) {
        float4v t4 = *(const float4v*)(qrow + ds * 16 + lg * 4);
#pragma unroll
        for (int j = 0; j < 4; ++j) qf[ds][j] = (_Float16)(t4[j] * 0.125f);
    }

    const float* kh_ = kg + (size_t)h * TT * DD;
    const float* vh_ = vg + (size_t)h * TT * DD;

    // staging assignments
    const int srow = tid >> 2;          // K key row 0..63
    const int sch  = (tid & 3) << 4;    // K float chunk base (16 floats)
    const int vd   = tid & 63;          // Vt row (d column of V)

    // swizzled write offsets (bytes, loop-invariant)
    unsigned kwr[4], vwr[4];
#pragma unroll
    for (int i = 0; i < 4; ++i) {
        const int ko8 = (tid & 3) * 4 + i;
        kwr[i] = (unsigned)(srow * 128 + 16 * ((ko8 >> 1) ^ (srow & 7)) +
                            8 * ((ko8 & 1) ^ ((srow >> 3) & 1)));
        const int vo8 = wave * 4 + i;
        vwr[i] = (unsigned)(vd * 128 + 16 * ((vo8 >> 1) ^ (vd & 7)) +
                            8 * ((vo8 & 1) ^ ((vd >> 3) & 1)));
    }
    // swizzled fragment-read bases (bytes): rbase[x] + y*2048
    unsigned rbase[4];
#pragma unroll
    for (int i = 0; i < 4; ++i)
        rbase[i] = (unsigned)(lr * 128 + 16 * (((2 * i + (lg >> 1))) ^ (lr & 7)) +
                              8 * ((lg & 1) ^ ((lr >> 3) & 1)));

    // prefetch registers
    float4v kq[4];
    float vv[16];

    const int t0k = blo & ~63;
#define ISSUE(KT)                                                              \
    {                                                                          \
        int krow = (KT) + srow; if (krow > TT - 1) krow = TT - 1;              \
        const float4v* kp = (const float4v*)(kh_ + (size_t)krow * DD + sch);   \
        kq[0] = kp[0]; kq[1] = kp[1]; kq[2] = kp[2]; kq[3] = kp[3];            \
        _Pragma("unroll")                                                      \
        for (int c = 0; c < 16; ++c) {                                         \
            int vrow = (KT) + wave * 16 + c; if (vrow > TT - 1) vrow = TT - 1; \
            vv[c] = vh_[(size_t)vrow * DD + vd];                               \
        }                                                                      \
    }

    ISSUE(t0k);

    float4v acc[4];
#pragma unroll
    for (int dt = 0; dt < 4; ++dt) acc[dt] = (float4v){0.f, 0.f, 0.f, 0.f};
    float m_run = -1e30f, lsum = 0.f;

    int cur = 0;
    for (int kt = t0k; kt < bhi; kt += 64) {
        // ---- pack + write LDS buf[cur] ----
        {
            char* Kb = (char*)Kl[cur];
            char* Vb = (char*)Vl[cur];
#pragma unroll
            for (int i = 0; i < 4; ++i) {
                half4 hk;
#pragma unroll
                for (int m = 0; m < 4; ++m) hk[m] = (_Float16)kq[i][m];
                *(half4*)(Kb + kwr[i]) = hk;
            }
#pragma unroll
            for (int i = 0; i < 4; ++i) {
                half4 hv;
#pragma unroll
                for (int m = 0; m < 4; ++m) hv[m] = (_Float16)vv[4 * i + m];
                *(half4*)(Vb + vwr[i]) = hv;
            }
        }
        __syncthreads();   // the only barrier per tile

        if (kt + 64 < bhi) ISSUE(kt + 64);   // wave-uniform

        if (!(kt + 64 <= wlo || kt >= whi)) {
            const char* Kb = (const char*)Kl[cur];
            const char* Vb = (const char*)Vl[cur];

            // ---- QK^T: St[key][q], 4 x 16-key quarters ----
            float st[4][4];
            const bool fullv = (kt >= mlo) && (kt + 64 <= mhi);  // wave-uniform
            __builtin_amdgcn_s_setprio(1);
#pragma unroll
            for (int t = 0; t < 4; ++t) {
                float4v sa = (float4v){0.f, 0.f, 0.f, 0.f};
#pragma unroll
                for (int ds = 0; ds < 4; ++ds) {
                    half4 kf = *(const half4*)(Kb + rbase[ds] + t * 2048);
                    sa = __builtin_amdgcn_mfma_f32_16x16x16f16(kf, qf[ds], sa, 0, 0, 0);
                }
                if (fullv) {
#pragma unroll
                    for (int j = 0; j < 4; ++j) st[t][j] = sa[j];
                } else {
#pragma unroll
                    for (int j = 0; j < 4; ++j) {
                        const int key = kt + t * 16 + lg * 4 + j;
                        st[t][j] = (key >= lo && key < hi) ? sa[j] : -1e30f;
                    }
                }
            }
            __builtin_amdgcn_s_setprio(0);

            // ---- online softmax (per q row = lr; reduce over lg) ----
            float tx = -1e30f;
#pragma unroll
            for (int t = 0; t < 4; ++t)
#pragma unroll
                for (int j = 0; j < 4; ++j) tx = fmaxf(tx, st[t][j]);
            tx = fmaxf(tx, __shfl_xor(tx, 16));
            tx = fmaxf(tx, __shfl_xor(tx, 32));

            // defer-max: only rescale when some row's max grew past m+8
            if (__any(tx > m_run + 8.f)) {
                const float mn = fmaxf(m_run, tx);
                const float a  = __expf(m_run - mn);
                lsum *= a;
#pragma unroll
                for (int dt = 0; dt < 4; ++dt)
#pragma unroll
                    for (int j = 0; j < 4; ++j) acc[dt][j] *= a;
                m_run = mn;
            }
            // all-masked rows (m==-1e30) produce p=1 garbage; self-heals: the
            // first real tile forces rescale with a=exp(-1e30-mn)=0 wiping acc,l.

            half4 pb[4];
            float ps = 0.f;
#pragma unroll
            for (int t = 0; t < 4; ++t)
#pragma unroll
                for (int j = 0; j < 4; ++j) {
                    const float e = __expf(st[t][j] - m_run);  // bounded by e^8
                    ps += e;
                    pb[t][j] = (_Float16)e;
                }
            ps += __shfl_xor(ps, 16);
            ps += __shfl_xor(ps, 32);
            lsum += ps;

            // ---- PV: Ot += V^T * P^T ----
            __builtin_amdgcn_s_setprio(1);
#pragma unroll
            for (int t = 0; t < 4; ++t)
#pragma unroll
                for (int dt = 0; dt < 4; ++dt) {
                    half4 vf = *(const half4*)(Vb + rbase[t] + dt * 2048);
                    acc[dt] = __builtin_amdgcn_mfma_f32_16x16x16f16(vf, pb[t], acc[dt], 0, 0, 0);
                }
            __builtin_amdgcn_s_setprio(0);
        }
        cur ^= 1;
    }

    const float inv = 1.0f / lsum;
    float* orow = outg + ((size_t)h * TT + q) * DD;
#pragma unroll
    for (int dt = 0; dt < 4; ++dt) {
        float4v o;
#pragma unroll
        for (int j = 0; j < 4; ++j) o[j] = acc[dt][j] * inv;
        *(float4v*)(orow + dt * 16 + lg * 4) = o;
    }
#undef ISSUE
}

extern "C" void kernel_launch(void* const* d_in, const int* in_sizes, int n_in,
                              void* d_out, int out_size, void* d_ws, size_t ws_size,
                              hipStream_t stream) {
    const float* q  = (const float*)d_in[0];
    const float* k  = (const float*)d_in[1];
    const float* v  = (const float*)d_in[2];
    const int*   cu = (const int*)d_in[3];
    float* out = (float*)d_out;

    dim3 grid(HH * (TT / 64));   // 1024
    dim3 block(256);
    hipLaunchKernelGGL(pa_fwd, grid, block, 0, stream, q, k, v, cu, out);
}